// Round 2
// baseline (502.764 us; speedup 1.0000x reference)
//
#include <hip/hip_runtime.h>
#include <hip/hip_bf16.h>

#define BQ   256
#define NTR  50000
#define DD   3072
#define NSP  50048          // padded N stride (multiple of 64)
#define CAP  4096
#define DELTA 18.0f

typedef __fp16 f16;
typedef __fp16 f16x2 __attribute__((ext_vector_type(2)));
typedef __fp16 f16x8 __attribute__((ext_vector_type(8)));
typedef float  f32x4 __attribute__((ext_vector_type(4)));

// ---------------- P0: convert x (f32) -> fp16 ----------------
__global__ __launch_bounds__(256) void kx(const float* __restrict__ x, f16* __restrict__ xh) {
    int i = blockIdx.x * 256 + threadIdx.x;          // 196608 float4s exactly
    f32x4 v = ((const f32x4*)x)[i];
    f16x2 a = __builtin_amdgcn_cvt_pkrtz(v[0], v[1]);
    f16x2 b = __builtin_amdgcn_cvt_pkrtz(v[2], v[3]);
    f16x2* o = (f16x2*)(xh + (size_t)i * 4);
    o[0] = a; o[1] = b;
}

// ---------------- P1: S = X * Y^T (fp16 MFMA), fused y2 ----------------
// tile: 256 (all queries) x 64 keys, BK=64. 256 threads = 4 waves, each wave 64x64.
__global__ __launch_bounds__(256) void kqk(
    const f16* __restrict__ xh, const float* __restrict__ y,
    float* __restrict__ S, float* __restrict__ y2o) {
    __shared__ char As[32768];   // 256 rows x 128 B (fp16), XOR-swizzled
    __shared__ char Bs[8192];    // 64 rows  x 128 B

    const int tid = threadIdx.x;
    const int n0  = blockIdx.x * 64;

    // y staging: thread -> (row ry, 16-elem k slice)
    const int ry   = tid >> 2;
    const int kp   = (tid & 3) << 4;
    const int yrow = n0 + ry;
    const bool yval = yrow < NTR;
    const float* ybase = y + (size_t)yrow * DD + kp;
    const int bsw = (ry & 7) << 4;
    char* bw0 = Bs + ry * 128 + (((kp << 1) +  0) ^ bsw);
    char* bw1 = Bs + ry * 128 + (((kp << 1) + 16) ^ bsw);

    // x staging: thread tid -> row tid, full 64-elem slice (8 x 16B chunks)
    const f16* xbase = xh + (size_t)tid * DD;
    char* awr = As + tid * 128;
    const int xsw = (tid & 7) << 4;

    // mfma mapping
    const int w = tid >> 6, l = tid & 63;
    const int l15 = l & 15, lg = l >> 4;
    const int kfb = lg << 4;             // byte offset of this lane's 8-elem k group

    f32x4 acc[4][4] = {};
    float y2a = 0.f;

    for (int ks = 0; ks < 48; ++ks) {
        // ---- stage y: 16 f32 -> 16 fp16 + y2 partial
        f32x4 v0, v1, v2, v3;
        if (yval) {
            const f32x4* p = (const f32x4*)(ybase + (ks << 6));
            v0 = p[0]; v1 = p[1]; v2 = p[2]; v3 = p[3];
        } else {
            v0 = 0.f; v1 = 0.f; v2 = 0.f; v3 = 0.f;
        }
        y2a += v0[0]*v0[0] + v0[1]*v0[1] + v0[2]*v0[2] + v0[3]*v0[3]
             + v1[0]*v1[0] + v1[1]*v1[1] + v1[2]*v1[2] + v1[3]*v1[3]
             + v2[0]*v2[0] + v2[1]*v2[1] + v2[2]*v2[2] + v2[3]*v2[3]
             + v3[0]*v3[0] + v3[1]*v3[1] + v3[2]*v3[2] + v3[3]*v3[3];
        union { f16x2 h2[4]; f16x8 h8; } u0, u1;
        u0.h2[0] = __builtin_amdgcn_cvt_pkrtz(v0[0], v0[1]);
        u0.h2[1] = __builtin_amdgcn_cvt_pkrtz(v0[2], v0[3]);
        u0.h2[2] = __builtin_amdgcn_cvt_pkrtz(v1[0], v1[1]);
        u0.h2[3] = __builtin_amdgcn_cvt_pkrtz(v1[2], v1[3]);
        u1.h2[0] = __builtin_amdgcn_cvt_pkrtz(v2[0], v2[1]);
        u1.h2[1] = __builtin_amdgcn_cvt_pkrtz(v2[2], v2[3]);
        u1.h2[2] = __builtin_amdgcn_cvt_pkrtz(v3[0], v3[1]);
        u1.h2[3] = __builtin_amdgcn_cvt_pkrtz(v3[2], v3[3]);
        *(f16x8*)bw0 = u0.h8;
        *(f16x8*)bw1 = u1.h8;
        // ---- stage x (already fp16 in ws)
        const f16x8* xp8 = (const f16x8*)(xbase + (ks << 6));
        #pragma unroll
        for (int c = 0; c < 8; ++c)
            *(f16x8*)(awr + ((c << 4) ^ xsw)) = xp8[c];
        __syncthreads();
        // ---- MFMA
        #pragma unroll
        for (int kk = 0; kk < 2; ++kk) {
            f16x8 af[4], bf[4];
            #pragma unroll
            for (int fm = 0; fm < 4; ++fm) {
                int r = (w << 6) + (fm << 4) + l15;
                af[fm] = *(const f16x8*)(As + r * 128 + (((kk << 6) + kfb) ^ ((r & 7) << 4)));
            }
            #pragma unroll
            for (int fn = 0; fn < 4; ++fn) {
                int r = (fn << 4) + l15;
                bf[fn] = *(const f16x8*)(Bs + r * 128 + (((kk << 6) + kfb) ^ ((r & 7) << 4)));
            }
            #pragma unroll
            for (int fm = 0; fm < 4; ++fm)
                #pragma unroll
                for (int fn = 0; fn < 4; ++fn)
                    acc[fm][fn] = __builtin_amdgcn_mfma_f32_16x16x32_f16(af[fm], bf[fn], acc[fm][fn], 0, 0, 0);
        }
        __syncthreads();
    }
    // y2: combine 4 threads/row (adjacent lanes), one write per row
    y2a += __shfl_xor(y2a, 1, 64);
    y2a += __shfl_xor(y2a, 2, 64);
    if ((tid & 3) == 0) y2o[yrow] = y2a;      // yrow < 50048 always; padded rows get 0
    // store S (C layout: col = lane&15, row = (lane>>4)*4 + reg)
    #pragma unroll
    for (int fm = 0; fm < 4; ++fm) {
        int row0 = (w << 6) + (fm << 4) + (lg << 2);
        #pragma unroll
        for (int fn = 0; fn < 4; ++fn) {
            int col = n0 + (fn << 4) + l15;
            float* sp = S + (size_t)row0 * NSP + col;
            sp[0]               = acc[fm][fn][0];
            sp[NSP]             = acc[fm][fn][1];
            sp[2 * (size_t)NSP] = acc[fm][fn][2];
            sp[3 * (size_t)NSP] = acc[fm][fn][3];
        }
    }
}

// ---------------- P2: per-row max + candidate selection ----------------
__global__ __launch_bounds__(256) void ksel(
    const float* __restrict__ S, const float* __restrict__ y2,
    const float* __restrict__ sig, unsigned* __restrict__ cnt,
    unsigned* __restrict__ cand) {
    __shared__ float red[8];
    const int b = blockIdx.x, tid = threadIdx.x;
    const float s2 = sig[b] * sig[b];
    const float* row = S + (size_t)b * NSP;
    float mx = -3.4e38f;
    for (int n = tid; n < NTR; n += 256)
        mx = fmaxf(mx, row[n] - 0.5f * y2[n]);
    #pragma unroll
    for (int o = 1; o < 64; o <<= 1) mx = fmaxf(mx, __shfl_xor(mx, o, 64));
    if ((tid & 63) == 0) red[tid >> 6] = mx;
    __syncthreads();
    mx = fmaxf(fmaxf(red[0], red[1]), fmaxf(red[2], red[3]));
    const float thr = mx - DELTA * s2;
    for (int n = tid; n < NTR; n += 256) {
        float v = row[n] - 0.5f * y2[n];
        if (v >= thr) {
            unsigned idx = atomicAdd(&cnt[b], 1u);
            if (idx < CAP) cand[(size_t)b * CAP + idx] = (unsigned)n;
        }
    }
}

// ---------------- P3: exact rescoring + softmax + sparse PV ----------------
__global__ __launch_bounds__(256) void kpv(
    const float* __restrict__ x, const float* __restrict__ y,
    const float* __restrict__ sig, const unsigned* __restrict__ cnt,
    const unsigned* __restrict__ cand, float* __restrict__ out) {
    __shared__ float xs[DD];
    __shared__ float tv[CAP];
    __shared__ unsigned ci[CAP];
    __shared__ float red[8];
    const int b = blockIdx.x, tid = threadIdx.x;
    const int c = (int)(cnt[b] < (unsigned)CAP ? cnt[b] : (unsigned)CAP);
    const float s2 = sig[b] * sig[b];
    const float isc = -0.5f / s2;
    for (int i = tid; i < DD; i += 256) xs[i] = x[(size_t)b * DD + i];
    for (int i = tid; i < c; i += 256) ci[i] = cand[(size_t)b * CAP + i];
    __syncthreads();
    // phase A: exact -0.5*||x-y||^2 / s2 per candidate (one wave per candidate)
    const int w = tid >> 6, l = tid & 63;
    for (int i = w; i < c; i += 4) {
        const f32x4* yr = (const f32x4*)(y + (size_t)ci[i] * DD);
        const f32x4* xr = (const f32x4*)xs;
        float d2 = 0.f;
        #pragma unroll
        for (int j = 0; j < 12; ++j) {
            f32x4 yv = yr[(j << 6) + l];
            f32x4 xv = xr[(j << 6) + l];
            float a0 = xv[0]-yv[0], a1 = xv[1]-yv[1], a2 = xv[2]-yv[2], a3 = xv[3]-yv[3];
            d2 += a0*a0 + a1*a1 + a2*a2 + a3*a3;
        }
        #pragma unroll
        for (int o = 1; o < 64; o <<= 1) d2 += __shfl_xor(d2, o, 64);
        if (l == 0) tv[i] = d2 * isc;
    }
    __syncthreads();
    // phase B: exact softmax over tv[0..c)
    float ml = -3.4e38f;
    for (int i = tid; i < c; i += 256) ml = fmaxf(ml, tv[i]);
    #pragma unroll
    for (int o = 1; o < 64; o <<= 1) ml = fmaxf(ml, __shfl_xor(ml, o, 64));
    if ((tid & 63) == 0) red[tid >> 6] = ml;
    __syncthreads();
    const float M = fmaxf(fmaxf(red[0], red[1]), fmaxf(red[2], red[3]));
    __syncthreads();
    float ls = 0.f;
    for (int i = tid; i < c; i += 256) ls += __expf(tv[i] - M);
    #pragma unroll
    for (int o = 1; o < 64; o <<= 1) ls += __shfl_xor(ls, o, 64);
    if ((tid & 63) == 0) red[tid >> 6] = ls;
    __syncthreads();
    const float L = red[0] + red[1] + red[2] + red[3];
    const float invL = 1.f / L;
    __syncthreads();
    for (int i = tid; i < c; i += 256) tv[i] = __expf(tv[i] - M) * invL;
    __syncthreads();
    // phase C: out[b][:] = sum_i w_i * y[ci[i]][:]
    f32x4 o0 = 0.f, o1 = 0.f, o2 = 0.f;
    for (int i = 0; i < c; ++i) {
        float wi = tv[i];
        const f32x4* yr = (const f32x4*)(y + (size_t)ci[i] * DD);
        f32x4 a = yr[tid], bb = yr[tid + 256], cc = yr[tid + 512];
        o0 += wi * a; o1 += wi * bb; o2 += wi * cc;
    }
    f32x4* od = (f32x4*)(out + (size_t)b * DD);
    od[tid] = o0; od[tid + 256] = o1; od[tid + 512] = o2;
}

extern "C" void kernel_launch(void* const* d_in, const int* in_sizes, int n_in,
                              void* d_out, int out_size, void* d_ws, size_t ws_size,
                              hipStream_t stream) {
    const float* x   = (const float*)d_in[0];
    const float* sig = (const float*)d_in[1];
    const float* y   = (const float*)d_in[2];
    float* out = (float*)d_out;
    char* ws = (char*)d_ws;
    // ws layout (bytes):
    f16*      xh   = (f16*)(ws);                  // 256*3072*2   = 1,572,864
    float*    y2   = (float*)(ws + 1572864);      // 50048*4      =   200,192
    unsigned* cnt  = (unsigned*)(ws + 1773056);   // 256*4        =     1,024
    unsigned* cand = (unsigned*)(ws + 1774080);   // 256*4096*4   = 4,194,304
    float*    S    = (float*)(ws + 5968384);      // 256*50048*4  = 51,249,152 (total ~57.2 MB)

    (void)hipMemsetAsync(cnt, 0, 256 * sizeof(unsigned), stream);
    kx  <<<768, 256, 0, stream>>>(x, xh);
    kqk <<<782, 256, 0, stream>>>(xh, y, S, y2);
    ksel<<<256, 256, 0, stream>>>(S, y2, sig, cnt, cand);
    kpv <<<256, 256, 0, stream>>>(x, y, sig, cnt, cand, out);
}

// Round 3
// 325.795 us; speedup vs baseline: 1.5432x; 1.5432x over previous
//
#include <hip/hip_runtime.h>
#include <hip/hip_bf16.h>

#define BQ   256
#define NTR  50000
#define DD   3072
#define NSP  50048          // padded N stride (multiple of 64)
#define CAP  4096
#define DELTA 18.0f

typedef __fp16 f16;
typedef __fp16 f16x2 __attribute__((ext_vector_type(2)));
typedef __fp16 f16x8 __attribute__((ext_vector_type(8)));
typedef float  f32x4 __attribute__((ext_vector_type(4)));

// ---------------- P0: convert x (f32) -> fp16, fragment-major pack ----------------
// Layout: 16B chunk index g = k>>3 (0..383), address = (g*256 + r) in f16x8 units.
// kqk lane then loads its A-fragment (row r, k-elems g*8..g*8+7) fully coalesced.
__global__ __launch_bounds__(256) void kx(const float* __restrict__ x, f16* __restrict__ xp) {
    const int t = blockIdx.x * 256 + threadIdx.x;   // t = g*256 + r, grid = 384*256
    const int g = t >> 8, r = t & 255;
    const f32x4* src = (const f32x4*)(x + (size_t)r * DD + (g << 3));
    f32x4 a = src[0], b = src[1];
    union { f16x2 h2[4]; f16x8 h8; } u;
    u.h2[0] = __builtin_amdgcn_cvt_pkrtz(a[0], a[1]);
    u.h2[1] = __builtin_amdgcn_cvt_pkrtz(a[2], a[3]);
    u.h2[2] = __builtin_amdgcn_cvt_pkrtz(b[0], b[1]);
    u.h2[3] = __builtin_amdgcn_cvt_pkrtz(b[2], b[3]);
    ((f16x8*)xp)[t] = u.h8;                         // consecutive tid -> coalesced
}

// ---------------- P1: S = X * Y^T (fp16 MFMA), fused y2 ----------------
// tile: 256 queries x 64 keys, BK=64. A direct-from-global (L2-resident packed),
// B double-buffered in LDS, one barrier/iter, y-loads pipelined 1 iter ahead.
__global__ __launch_bounds__(256, 2) void kqk(
    const f16* __restrict__ xp, const float* __restrict__ y,
    float* __restrict__ S, float* __restrict__ y2o) {
    __shared__ char Bs[2][8192];   // 64 rows x 128 B, XOR-swizzled

    const int tid = threadIdx.x;
    const int n0  = blockIdx.x * 64;

    // y staging: thread -> (row ry, 16-elem k slice)
    const int ry   = tid >> 2;
    const int kp   = (tid & 3) << 4;
    const int yrow = n0 + ry;
    const bool yval = yrow < NTR;
    const float* ybase = y + (size_t)yrow * DD + kp;
    const int bsw = (ry & 7) << 4;
    const int bw0 = ry * 128 + (((kp << 1) +  0) ^ bsw);
    const int bw1 = ry * 128 + (((kp << 1) + 16) ^ bsw);

    // mfma mapping
    const int w = tid >> 6, l = tid & 63;
    const int l15 = l & 15, lg = l >> 4;

    f32x4 acc[4][4] = {};
    float y2a = 0.f;
    f32x4 v0, v1, v2, v3;

    // stage y slice held in v0..v3 into buffer `buf`, accumulating y2
    auto cvtw = [&](int buf) {
        y2a += v0[0]*v0[0] + v0[1]*v0[1] + v0[2]*v0[2] + v0[3]*v0[3]
             + v1[0]*v1[0] + v1[1]*v1[1] + v1[2]*v1[2] + v1[3]*v1[3]
             + v2[0]*v2[0] + v2[1]*v2[1] + v2[2]*v2[2] + v2[3]*v2[3]
             + v3[0]*v3[0] + v3[1]*v3[1] + v3[2]*v3[2] + v3[3]*v3[3];
        union { f16x2 h2[4]; f16x8 h8; } u0, u1;
        u0.h2[0] = __builtin_amdgcn_cvt_pkrtz(v0[0], v0[1]);
        u0.h2[1] = __builtin_amdgcn_cvt_pkrtz(v0[2], v0[3]);
        u0.h2[2] = __builtin_amdgcn_cvt_pkrtz(v1[0], v1[1]);
        u0.h2[3] = __builtin_amdgcn_cvt_pkrtz(v1[2], v1[3]);
        u1.h2[0] = __builtin_amdgcn_cvt_pkrtz(v2[0], v2[1]);
        u1.h2[1] = __builtin_amdgcn_cvt_pkrtz(v2[2], v2[3]);
        u1.h2[2] = __builtin_amdgcn_cvt_pkrtz(v3[0], v3[1]);
        u1.h2[3] = __builtin_amdgcn_cvt_pkrtz(v3[2], v3[3]);
        *(f16x8*)(&Bs[buf][bw0]) = u0.h8;
        *(f16x8*)(&Bs[buf][bw1]) = u1.h8;
    };

    // prologue: y(0) -> Bs[0]
    if (yval) { const f32x4* p = (const f32x4*)ybase; v0 = p[0]; v1 = p[1]; v2 = p[2]; v3 = p[3]; }
    else      { v0 = 0.f; v1 = 0.f; v2 = 0.f; v3 = 0.f; }
    cvtw(0);
    __syncthreads();

    const f16x8* ap = (const f16x8*)xp;
    const int arow = (w << 6) + l15;

    for (int ks = 0; ks < 48; ++ks) {
        const int cur = ks & 1;
        // A fragments direct from packed global (L2): issue FIRST so MFMA's
        // vmcnt wait does not cover the y prefetch below.
        f16x8 af[2][4];
        #pragma unroll
        for (int kk = 0; kk < 2; ++kk)
            #pragma unroll
            for (int fm = 0; fm < 4; ++fm)
                af[kk][fm] = ap[(size_t)((ks << 3) + (kk << 2) + lg) * 256 + arow + (fm << 4)];
        // y prefetch for ks+1 (HBM; consumed after MFMA)
        if (ks < 47) {
            if (yval) {
                const f32x4* p = (const f32x4*)(ybase + ((ks + 1) << 6));
                v0 = p[0]; v1 = p[1]; v2 = p[2]; v3 = p[3];
            } else { v0 = 0.f; v1 = 0.f; v2 = 0.f; v3 = 0.f; }
        }
        // B fragments from LDS
        f16x8 bf[2][4];
        #pragma unroll
        for (int kk = 0; kk < 2; ++kk)
            #pragma unroll
            for (int fn = 0; fn < 4; ++fn) {
                int r = (fn << 4) + l15;
                bf[kk][fn] = *(const f16x8*)(&Bs[cur][r * 128 + (((kk << 6) + (lg << 4)) ^ ((r & 7) << 4))]);
            }
        #pragma unroll
        for (int kk = 0; kk < 2; ++kk)
            #pragma unroll
            for (int fm = 0; fm < 4; ++fm)
                #pragma unroll
                for (int fn = 0; fn < 4; ++fn)
                    acc[fm][fn] = __builtin_amdgcn_mfma_f32_16x16x32_f16(af[kk][fm], bf[kk][fn], acc[fm][fn], 0, 0, 0);
        // write y(ks+1) into alternate buffer, then single barrier
        if (ks < 47) cvtw(cur ^ 1);
        __syncthreads();
    }

    // y2: combine 4 threads/row, one write per row
    y2a += __shfl_xor(y2a, 1, 64);
    y2a += __shfl_xor(y2a, 2, 64);
    if ((tid & 3) == 0) y2o[yrow] = y2a;
    // store S (C layout: col = lane&15, row = (lane>>4)*4 + reg)
    #pragma unroll
    for (int fm = 0; fm < 4; ++fm) {
        int row0 = (w << 6) + (fm << 4) + (lg << 2);
        #pragma unroll
        for (int fn = 0; fn < 4; ++fn) {
            int col = n0 + (fn << 4) + l15;
            float* sp = S + (size_t)row0 * NSP + col;
            sp[0]               = acc[fm][fn][0];
            sp[NSP]             = acc[fm][fn][1];
            sp[2 * (size_t)NSP] = acc[fm][fn][2];
            sp[3 * (size_t)NSP] = acc[fm][fn][3];
        }
    }
}

// ---------------- P2: per-row max + candidate selection (f32x4) ----------------
__global__ __launch_bounds__(256) void ksel(
    const float* __restrict__ S, const float* __restrict__ y2,
    const float* __restrict__ sig, unsigned* __restrict__ cnt,
    unsigned* __restrict__ cand) {
    __shared__ float red[4];
    const int b = blockIdx.x, tid = threadIdx.x;
    const float s2 = sig[b] * sig[b];
    const f32x4* rowv = (const f32x4*)(S + (size_t)b * NSP);
    const f32x4* y2v  = (const f32x4*)y2;
    float mx = -3.4e38f;
    for (int i = tid; i < 12500; i += 256) {       // 12500*4 = 50000 exactly
        f32x4 s = rowv[i], q = y2v[i];
        mx = fmaxf(mx, fmaxf(fmaxf(s[0] - 0.5f*q[0], s[1] - 0.5f*q[1]),
                             fmaxf(s[2] - 0.5f*q[2], s[3] - 0.5f*q[3])));
    }
    #pragma unroll
    for (int o = 1; o < 64; o <<= 1) mx = fmaxf(mx, __shfl_xor(mx, o, 64));
    if ((tid & 63) == 0) red[tid >> 6] = mx;
    __syncthreads();
    mx = fmaxf(fmaxf(red[0], red[1]), fmaxf(red[2], red[3]));
    const float thr = mx - DELTA * s2;
    for (int i = tid; i < 12500; i += 256) {
        f32x4 s = rowv[i], q = y2v[i];
        #pragma unroll
        for (int j = 0; j < 4; ++j) {
            float v = s[j] - 0.5f * q[j];
            if (v >= thr) {
                unsigned idx = atomicAdd(&cnt[b], 1u);
                if (idx < CAP) cand[(size_t)b * CAP + idx] = (unsigned)(4 * i + j);
            }
        }
    }
}

// ---------------- P3: exact rescoring + softmax + sparse PV ----------------
__global__ __launch_bounds__(256) void kpv(
    const float* __restrict__ x, const float* __restrict__ y,
    const float* __restrict__ sig, const unsigned* __restrict__ cnt,
    const unsigned* __restrict__ cand, float* __restrict__ out) {
    __shared__ float xs[DD];
    __shared__ float tv[CAP];
    __shared__ unsigned ci[CAP];
    __shared__ float red[8];
    const int b = blockIdx.x, tid = threadIdx.x;
    const int c = (int)(cnt[b] < (unsigned)CAP ? cnt[b] : (unsigned)CAP);
    const float s2 = sig[b] * sig[b];
    const float isc = -0.5f / s2;
    for (int i = tid; i < DD; i += 256) xs[i] = x[(size_t)b * DD + i];
    for (int i = tid; i < c; i += 256) ci[i] = cand[(size_t)b * CAP + i];
    __syncthreads();
    // phase A: exact -0.5*||x-y||^2 / s2 per candidate (one wave per candidate)
    const int w = tid >> 6, l = tid & 63;
    for (int i = w; i < c; i += 4) {
        const f32x4* yr = (const f32x4*)(y + (size_t)ci[i] * DD);
        const f32x4* xr = (const f32x4*)xs;
        float d2 = 0.f;
        #pragma unroll
        for (int j = 0; j < 12; ++j) {
            f32x4 yv = yr[(j << 6) + l];
            f32x4 xv = xr[(j << 6) + l];
            float a0 = xv[0]-yv[0], a1 = xv[1]-yv[1], a2 = xv[2]-yv[2], a3 = xv[3]-yv[3];
            d2 += a0*a0 + a1*a1 + a2*a2 + a3*a3;
        }
        #pragma unroll
        for (int o = 1; o < 64; o <<= 1) d2 += __shfl_xor(d2, o, 64);
        if (l == 0) tv[i] = d2 * isc;
    }
    __syncthreads();
    // phase B: exact softmax over tv[0..c)
    float ml = -3.4e38f;
    for (int i = tid; i < c; i += 256) ml = fmaxf(ml, tv[i]);
    #pragma unroll
    for (int o = 1; o < 64; o <<= 1) ml = fmaxf(ml, __shfl_xor(ml, o, 64));
    if ((tid & 63) == 0) red[tid >> 6] = ml;
    __syncthreads();
    const float M = fmaxf(fmaxf(red[0], red[1]), fmaxf(red[2], red[3]));
    __syncthreads();
    float ls = 0.f;
    for (int i = tid; i < c; i += 256) ls += __expf(tv[i] - M);
    #pragma unroll
    for (int o = 1; o < 64; o <<= 1) ls += __shfl_xor(ls, o, 64);
    if ((tid & 63) == 0) red[tid >> 6] = ls;
    __syncthreads();
    const float L = red[0] + red[1] + red[2] + red[3];
    const float invL = 1.f / L;
    __syncthreads();
    for (int i = tid; i < c; i += 256) tv[i] = __expf(tv[i] - M) * invL;
    __syncthreads();
    // phase C: out[b][:] = sum_i w_i * y[ci[i]][:]
    f32x4 o0 = 0.f, o1 = 0.f, o2 = 0.f;
    for (int i = 0; i < c; ++i) {
        float wi = tv[i];
        const f32x4* yr = (const f32x4*)(y + (size_t)ci[i] * DD);
        f32x4 a = yr[tid], bb = yr[tid + 256], cc = yr[tid + 512];
        o0 += wi * a; o1 += wi * bb; o2 += wi * cc;
    }
    f32x4* od = (f32x4*)(out + (size_t)b * DD);
    od[tid] = o0; od[tid + 256] = o1; od[tid + 512] = o2;
}

extern "C" void kernel_launch(void* const* d_in, const int* in_sizes, int n_in,
                              void* d_out, int out_size, void* d_ws, size_t ws_size,
                              hipStream_t stream) {
    const float* x   = (const float*)d_in[0];
    const float* sig = (const float*)d_in[1];
    const float* y   = (const float*)d_in[2];
    float* out = (float*)d_out;
    char* ws = (char*)d_ws;
    // ws layout (bytes):
    f16*      xp   = (f16*)(ws);                  // 256*3072*2   = 1,572,864
    float*    y2   = (float*)(ws + 1572864);      // 50048*4      =   200,192
    unsigned* cnt  = (unsigned*)(ws + 1773056);   // 256*4        =     1,024
    unsigned* cand = (unsigned*)(ws + 1774080);   // 256*4096*4   = 4,194,304
    float*    S    = (float*)(ws + 5968384);      // 256*50048*4  = 51,249,152 (total ~57.2 MB)

    (void)hipMemsetAsync(cnt, 0, 256 * sizeof(unsigned), stream);
    kx  <<<384, 256, 0, stream>>>(x, xp);
    kqk <<<782, 256, 0, stream>>>(xp, y, S, y2);
    ksel<<<256, 256, 0, stream>>>(S, y2, sig, cnt, cand);
    kpv <<<256, 256, 0, stream>>>(x, y, sig, cnt, cand, out);
}

// Round 4
// 291.072 us; speedup vs baseline: 1.7273x; 1.1193x over previous
//
#include <hip/hip_runtime.h>
#include <hip/hip_bf16.h>
#include <type_traits>

#define BQ   256
#define NTR  50000
#define DD   3072
#define NSP  50048          // padded N stride (multiple of 64)
#define NBLK 782
#define CAP  4096
#define DELTA 18.0f

typedef __fp16 f16;
typedef __fp16 f16x2 __attribute__((ext_vector_type(2)));
typedef __fp16 f16x8 __attribute__((ext_vector_type(8)));
typedef float  f32x4 __attribute__((ext_vector_type(4)));

// ---------------- P0: convert x (f32) -> fp16, fragment-major pack ----------------
__global__ __launch_bounds__(256) void kx(const float* __restrict__ x, f16* __restrict__ xp) {
    const int t = blockIdx.x * 256 + threadIdx.x;   // t = g*256 + r, grid = 384*256
    const int g = t >> 8, r = t & 255;
    const f32x4* src = (const f32x4*)(x + (size_t)r * DD + (g << 3));
    f32x4 a = src[0], b = src[1];
    union { f16x2 h2[4]; f16x8 h8; } u;
    u.h2[0] = __builtin_amdgcn_cvt_pkrtz(a[0], a[1]);
    u.h2[1] = __builtin_amdgcn_cvt_pkrtz(a[2], a[3]);
    u.h2[2] = __builtin_amdgcn_cvt_pkrtz(b[0], b[1]);
    u.h2[3] = __builtin_amdgcn_cvt_pkrtz(b[2], b[3]);
    ((f16x8*)xp)[t] = u.h8;
}

// ---------------- P1: S = X*Y^T - 0.5*|y|^2 (fp16 MFMA), + per-block row max ----------------
// 256 queries x 64 keys, BK=64. A direct-from-L2 (packed), B double-buffered LDS.
// Depth-2 y prefetch in named P/Q register slots; raw barrier + lgkmcnt-only wait
// so HBM y-loads stay in flight across barriers.
__global__ __launch_bounds__(256, 2) void kqk(
    const f16* __restrict__ xp, const float* __restrict__ y,
    float* __restrict__ S, float* __restrict__ pmax) {
    __shared__ char Bs[2][8192];   // 64 rows x 128 B, XOR-swizzled

    const int tid = threadIdx.x;
    const int blk = blockIdx.x;
    const int n0  = blk * 64;

    const int ry   = tid >> 2;
    const int kp   = (tid & 3) << 4;
    const int yrow = n0 + ry;
    const bool yval = yrow < NTR;
    const float* ybase = y + (size_t)yrow * DD + kp;
    const int bsw = (ry & 7) << 4;
    const int bo0 = ry * 128 + (((kp << 1) +  0) ^ bsw);
    const int bo1 = ry * 128 + (((kp << 1) + 16) ^ bsw);

    const int w = tid >> 6, l = tid & 63;
    const int l15 = l & 15, lg = l >> 4;

    f32x4 acc[4][4] = {};
    float y2a = 0.f;
    f32x4 p0, p1, p2, p3, q0, q1, q2, q3;

    auto loady = [&](f32x4& a0, f32x4& a1, f32x4& a2, f32x4& a3, int ks) {
        if (yval) {
            const f32x4* p = (const f32x4*)(ybase + (ks << 6));
            a0 = p[0]; a1 = p[1]; a2 = p[2]; a3 = p[3];
        } else { a0 = 0.f; a1 = 0.f; a2 = 0.f; a3 = 0.f; }
    };
    auto cvtw = [&](f32x4& a0, f32x4& a1, f32x4& a2, f32x4& a3, int buf) {
        y2a += a0[0]*a0[0] + a0[1]*a0[1] + a0[2]*a0[2] + a0[3]*a0[3]
             + a1[0]*a1[0] + a1[1]*a1[1] + a1[2]*a1[2] + a1[3]*a1[3]
             + a2[0]*a2[0] + a2[1]*a2[1] + a2[2]*a2[2] + a2[3]*a2[3]
             + a3[0]*a3[0] + a3[1]*a3[1] + a3[2]*a3[2] + a3[3]*a3[3];
        union { f16x2 h2[4]; f16x8 h8; } u0, u1;
        u0.h2[0] = __builtin_amdgcn_cvt_pkrtz(a0[0], a0[1]);
        u0.h2[1] = __builtin_amdgcn_cvt_pkrtz(a0[2], a0[3]);
        u0.h2[2] = __builtin_amdgcn_cvt_pkrtz(a1[0], a1[1]);
        u0.h2[3] = __builtin_amdgcn_cvt_pkrtz(a1[2], a1[3]);
        u1.h2[0] = __builtin_amdgcn_cvt_pkrtz(a2[0], a2[1]);
        u1.h2[1] = __builtin_amdgcn_cvt_pkrtz(a2[2], a2[3]);
        u1.h2[2] = __builtin_amdgcn_cvt_pkrtz(a3[0], a3[1]);
        u1.h2[3] = __builtin_amdgcn_cvt_pkrtz(a3[2], a3[3]);
        *(f16x8*)(&Bs[buf][bo0]) = u0.h8;
        *(f16x8*)(&Bs[buf][bo1]) = u1.h8;
    };

    // prologue: y(0)->Bs[0], y(1) in Q
    loady(p0, p1, p2, p3, 0);
    loady(q0, q1, q2, q3, 1);
    cvtw(p0, p1, p2, p3, 0);
    asm volatile("s_waitcnt lgkmcnt(0)" ::: "memory");
    __builtin_amdgcn_s_barrier();

    const f16x8* ap = (const f16x8*)xp;
    const int arow = (w << 6) + l15;

    auto iter = [&](int ks, auto curC,
                    f32x4& s0, f32x4& s1, f32x4& s2, f32x4& s3,    // prefetch slot (y(ks+2))
                    f32x4& t0, f32x4& t1, f32x4& t2, f32x4& t3) {  // cvt slot (y(ks+1))
        constexpr int cur = decltype(curC)::value;
        // A fragments from L2 (issued first; MFMA waits only these)
        f16x8 af[2][4];
        #pragma unroll
        for (int kk = 0; kk < 2; ++kk)
            #pragma unroll
            for (int fm = 0; fm < 4; ++fm)
                af[kk][fm] = ap[(size_t)((ks << 3) + (kk << 2) + lg) * 256 + arow + (fm << 4)];
        // y prefetch 2 ahead (stays in flight across the barrier)
        if (ks + 2 < 48) loady(s0, s1, s2, s3, ks + 2);
        // B fragments from LDS
        f16x8 bf[2][4];
        #pragma unroll
        for (int kk = 0; kk < 2; ++kk)
            #pragma unroll
            for (int fn = 0; fn < 4; ++fn) {
                int r = (fn << 4) + l15;
                bf[kk][fn] = *(const f16x8*)(&Bs[cur][r * 128 + (((kk << 6) + (lg << 4)) ^ ((r & 7) << 4))]);
            }
        #pragma unroll
        for (int kk = 0; kk < 2; ++kk)
            #pragma unroll
            for (int fm = 0; fm < 4; ++fm)
                #pragma unroll
                for (int fn = 0; fn < 4; ++fn)
                    acc[fm][fn] = __builtin_amdgcn_mfma_f32_16x16x32_f16(af[kk][fm], bf[kk][fn], acc[fm][fn], 0, 0, 0);
        // stage y(ks+1) into the other buffer
        if (ks + 1 < 48) cvtw(t0, t1, t2, t3, cur ^ 1);
        asm volatile("s_waitcnt lgkmcnt(0)" ::: "memory");
        __builtin_amdgcn_s_barrier();
    };

    for (int ks2 = 0; ks2 < 48; ks2 += 2) {
        iter(ks2,     std::integral_constant<int,0>{}, p0,p1,p2,p3, q0,q1,q2,q3);
        iter(ks2 + 1, std::integral_constant<int,1>{}, q0,q1,q2,q3, p0,p1,p2,p3);
    }

    // epilogue: y2 per row -> LDS broadcast
    float* lys = (float*)&Bs[0][0];
    y2a += __shfl_xor(y2a, 1, 64);
    y2a += __shfl_xor(y2a, 2, 64);
    if ((tid & 3) == 0) lys[ry] = y2a;
    __syncthreads();
    float ly2[4];
    #pragma unroll
    for (int fn = 0; fn < 4; ++fn) ly2[fn] = 0.5f * lys[(fn << 4) + l15];
    // per-row max over this block's 64 cols (pad cols masked)
    #pragma unroll
    for (int fm = 0; fm < 4; ++fm) {
        #pragma unroll
        for (int j = 0; j < 4; ++j) {
            float rm = -3.4e38f;
            #pragma unroll
            for (int fn = 0; fn < 4; ++fn) {
                int col = n0 + (fn << 4) + l15;
                float sc = acc[fm][fn][j] - ly2[fn];
                rm = (col < NTR) ? fmaxf(rm, sc) : rm;
            }
            #pragma unroll
            for (int off = 1; off < 16; off <<= 1) rm = fmaxf(rm, __shfl_xor(rm, off, 64));
            if (l15 == 0)
                pmax[(size_t)((w << 6) + (fm << 4) + (lg << 2) + j) * NBLK + blk] = rm;
        }
    }
    // S = x.y - 0.5|y|^2
    #pragma unroll
    for (int fm = 0; fm < 4; ++fm) {
        int row0 = (w << 6) + (fm << 4) + (lg << 2);
        #pragma unroll
        for (int fn = 0; fn < 4; ++fn) {
            int col = n0 + (fn << 4) + l15;
            float* sp = S + (size_t)row0 * NSP + col;
            sp[0]               = acc[fm][fn][0] - ly2[fn];
            sp[NSP]             = acc[fm][fn][1] - ly2[fn];
            sp[2 * (size_t)NSP] = acc[fm][fn][2] - ly2[fn];
            sp[3 * (size_t)NSP] = acc[fm][fn][3] - ly2[fn];
        }
    }
}

// ---------------- P2: row max from pmax + candidate selection ----------------
__global__ __launch_bounds__(256) void ksel(
    const float* __restrict__ S, const float* __restrict__ pmax,
    const float* __restrict__ sig, unsigned* __restrict__ cnt,
    unsigned* __restrict__ cand) {
    __shared__ float red[4];
    const int b = blockIdx.x, tid = threadIdx.x;
    const float s2 = sig[b] * sig[b];
    const float* pm = pmax + (size_t)b * NBLK;
    float mx = -3.4e38f;
    for (int i = tid; i < NBLK; i += 256) mx = fmaxf(mx, pm[i]);
    #pragma unroll
    for (int o = 1; o < 64; o <<= 1) mx = fmaxf(mx, __shfl_xor(mx, o, 64));
    if ((tid & 63) == 0) red[tid >> 6] = mx;
    __syncthreads();
    mx = fmaxf(fmaxf(red[0], red[1]), fmaxf(red[2], red[3]));
    const float thr = mx - DELTA * s2;
    const f32x4* rowv = (const f32x4*)(S + (size_t)b * NSP);
    for (int i = tid; i < 12500; i += 256) {
        f32x4 s = rowv[i];
        #pragma unroll
        for (int j = 0; j < 4; ++j) {
            if (s[j] >= thr) {
                unsigned idx = atomicAdd(&cnt[b], 1u);
                if (idx < CAP) cand[(size_t)b * CAP + idx] = (unsigned)(4 * i + j);
            }
        }
    }
}

// ---------------- P3: fused exact rescoring + online softmax + PV (one pass over rows) ----------------
__global__ __launch_bounds__(512) void kpv(
    const float* __restrict__ x, const float* __restrict__ y,
    const float* __restrict__ sig, const unsigned* __restrict__ cnt,
    const unsigned* __restrict__ cand, float* __restrict__ out) {
    __shared__ float xs[DD];
    __shared__ unsigned ci[CAP];
    __shared__ float om[8], ol[8];
    __shared__ float sumv[DD];
    const int b = blockIdx.x, tid = threadIdx.x;
    const int c = (int)(cnt[b] < (unsigned)CAP ? cnt[b] : (unsigned)CAP);
    const float s2 = sig[b] * sig[b];
    const float isc = -0.5f / s2;
    for (int i = tid; i < DD; i += 512) xs[i] = x[(size_t)b * DD + i];
    for (int i = tid; i < c; i += 512) ci[i] = cand[(size_t)b * CAP + i];
    __syncthreads();
    const int w = tid >> 6, l = tid & 63;
    const f32x4* xr = (const f32x4*)xs;

    f32x4 o[12] = {};
    float m = -3.4e38f, ll = 0.f;
    f32x4 A[12], Bv[12];

    auto LD = [&](f32x4* dst, int i) {
        const f32x4* yr = (const f32x4*)(y + (size_t)ci[i] * DD);
        #pragma unroll
        for (int j = 0; j < 12; ++j) dst[j] = yr[(j << 6) + l];
    };
    auto PROC = [&](f32x4* src) {
        float d2 = 0.f;
        #pragma unroll
        for (int j = 0; j < 12; ++j) {
            f32x4 xv = xr[(j << 6) + l];
            float a0 = xv[0]-src[j][0], a1 = xv[1]-src[j][1],
                  a2 = xv[2]-src[j][2], a3 = xv[3]-src[j][3];
            d2 += a0*a0 + a1*a1 + a2*a2 + a3*a3;
        }
        #pragma unroll
        for (int off = 1; off < 64; off <<= 1) d2 += __shfl_xor(d2, off, 64);
        float s = d2 * isc;
        float mn = fmaxf(m, s);
        float f = __expf(m - mn);
        float wi = __expf(s - mn);
        #pragma unroll
        for (int j = 0; j < 12; ++j) o[j] = o[j] * f + wi * src[j];
        ll = ll * f + wi;
        m = mn;
    };

    int i = w;
    if (i < c) LD(A, i);
    for (; i < c; i += 16) {
        int i2 = i + 8;
        if (i2 < c) LD(Bv, i2);
        PROC(A);
        if (i2 < c) {
            if (i + 16 < c) LD(A, i + 16);
            PROC(Bv);
        }
    }
    om[w] = m; ol[w] = ll;
    __syncthreads();
    float M = om[0];
    #pragma unroll
    for (int ww = 1; ww < 8; ++ww) M = fmaxf(M, om[ww]);
    float Ls = 0.f;
    #pragma unroll
    for (int ww = 0; ww < 8; ++ww) Ls += ol[ww] * __expf(om[ww] - M);
    const float fw = __expf(m - M);
    f32x4* sv = (f32x4*)sumv;
    if (w == 0) {
        #pragma unroll
        for (int j = 0; j < 12; ++j) sv[(j << 6) + l] = o[j] * fw;
    }
    __syncthreads();
    for (int ww = 1; ww < 8; ++ww) {
        if (w == ww) {
            #pragma unroll
            for (int j = 0; j < 12; ++j) sv[(j << 6) + l] += o[j] * fw;
        }
        __syncthreads();
    }
    const float inv = 1.f / Ls;
    f32x4* od = (f32x4*)(out + (size_t)b * DD);
    for (int t = tid; t < 768; t += 512) od[t] = sv[t] * inv;
}

extern "C" void kernel_launch(void* const* d_in, const int* in_sizes, int n_in,
                              void* d_out, int out_size, void* d_ws, size_t ws_size,
                              hipStream_t stream) {
    const float* x   = (const float*)d_in[0];
    const float* sig = (const float*)d_in[1];
    const float* y   = (const float*)d_in[2];
    float* out = (float*)d_out;
    char* ws = (char*)d_ws;
    f16*      xp   = (f16*)(ws);                  // 1,572,864
    unsigned* cnt  = (unsigned*)(ws + 1572864);   // 1,024
    unsigned* cand = (unsigned*)(ws + 1573888);   // 4,194,304
    float*    pmax = (float*)(ws + 5768192);      // 256*782*4 = 800,768
    float*    S    = (float*)(ws + 6568960);      // 256*50048*4 = 51,249,152

    (void)hipMemsetAsync(cnt, 0, 256 * sizeof(unsigned), stream);
    kx  <<<384, 256, 0, stream>>>(x, xp);
    kqk <<<NBLK, 256, 0, stream>>>(xp, y, S, pmax);
    ksel<<<256, 256, 0, stream>>>(S, pmax, sig, cnt, cand);
    kpv <<<256, 512, 0, stream>>>(x, y, sig, cnt, cand, out);
}